// Round 1
// baseline (1175.181 us; speedup 1.0000x reference)
//
#include <hip/hip_runtime.h>
#include <hip/hip_fp16.h>

typedef unsigned int u32;

// ---------------- problem sizes ----------------
#define B 8
#define S 160
#define H 128
#define H3 384
#define G4 512
#define CG 1536
#define WIN 300
#define VIN 35
#define AIN 74

// ---------------- workspace layout (float-word offsets) ----------------
#define XG_W   0
#define XG_V   (XG_W + B*S*G4)
#define XG_A   (XG_V + B*S*G4)
#define HS_W   (XG_A + B*S*G4)
#define HS_V   (HS_W + B*S*H)
#define HS_A   (HS_V + B*S*H)
#define S_VW   (HS_A + B*S*H)
#define T_VW   (S_VW + B*S*H)
#define S_AW   (T_VW + B*S*H)
#define T_AW   (S_AW + B*S*H)
#define C_X    (T_AW + B*S*H)
#define S_SA   (C_X + B*S*H3)
#define WIHT_W (S_SA + B*S*H3)
#define WIHT_V (WIHT_W + WIN*G4)
#define WIHT_A (WIHT_V + VIN*G4)
#define WIHT_C (WIHT_A + AIN*G4)
#define WHHT_W (WIHT_C + H3*CG)
#define WHHT_V (WHHT_W + H*G4)
#define WHHT_A (WHHT_V + H*G4)
#define SAT_S  (WHHT_A + H*G4)
#define SAT_T  (SAT_S + H3*H3)
#define VW_ST  (SAT_T + H3*H3)
#define VW_TT  (VW_ST + H*H)
#define AW_ST  (VW_TT + H*H)
#define AW_TT  (AW_ST + H*H)
#define BSUM_W (AW_TT + H*H)
#define BSUM_V (BSUM_W + G4)
#define BSUM_A (BSUM_V + G4)
#define BSUM_C (BSUM_A + G4)
#define VCOMP  (BSUM_C + CG)
#define ACOMP  (VCOMP + B*H)
#define C_OUT  (ACOMP + B*H)
// u32 regions
#define XGC16  (C_OUT + B*H3)
#define WRES   (XGC16 + B*S*CG/2)
#define CHS16  (WRES + CG*H3/2)
#define H_X    (CHS16 + B*S*H3/2)
#define CTR    (H_X + B*2*(H3/2))

// ---------------- output layout ----------------
#define O_VATT  8
#define O_VSOFT (8 + B*S*S)
#define O_AATT  (O_VSOFT + B*S)
#define O_ASOFT (O_AATT + B*S*S)

// ---------------- helpers ----------------
__device__ __forceinline__ float sigf(float x){ return 1.f/(1.f+__expf(-x)); }
__device__ __forceinline__ float tanhfast(float x){ float e=__expf(2.f*x); return 1.f - 2.f/(e+1.f); }
__device__ __forceinline__ float wred_sum(float x){
#pragma unroll
  for (int o=32;o;o>>=1) x += __shfl_xor(x,o);
  return x;
}
__device__ __forceinline__ float wred_max(float x){
#pragma unroll
  for (int o=32;o;o>>=1) x = fmaxf(x,__shfl_xor(x,o));
  return x;
}
__device__ __forceinline__ u32 packh2(float lo, float hi){
  __half a=__float2half_rn(lo), b=__float2half_rn(hi);
  return ((u32)__half_as_ushort(b)<<16) | (u32)__half_as_ushort(a);
}

typedef _Float16 h2v __attribute__((ext_vector_type(2)));
#if defined(__has_builtin)
#if __has_builtin(__builtin_amdgcn_fdot2)
#define HAVE_FDOT2 1
#endif
#endif
__device__ __forceinline__ float fdot2f(u32 w, u32 h, float acc){
#ifdef HAVE_FDOT2
  return __builtin_amdgcn_fdot2(__builtin_bit_cast(h2v,w), __builtin_bit_cast(h2v,h), acc, false);
#else
  h2v a=__builtin_bit_cast(h2v,w), b=__builtin_bit_cast(h2v,h);
  return acc + (float)a.x*(float)b.x + (float)a.y*(float)b.y;
#endif
}

// ---------------- K0: prep (transposes, bias sums, f16 packs, counter zero) ----------------
#define PREP_TOT (2*B + 3*G4 + CG + WIN*G4 + VIN*G4 + AIN*G4 + H3*CG + 3*H*G4 + 2*H3*H3 + 4*H*H + CG*H3/2)
__global__ void k0_prep(float* __restrict__ ws, u32* __restrict__ wsu,
    const float* __restrict__ wWih, const float* __restrict__ wWhh, const float* __restrict__ wbih, const float* __restrict__ wbhh,
    const float* __restrict__ vWih, const float* __restrict__ vWhh, const float* __restrict__ vbih, const float* __restrict__ vbhh,
    const float* __restrict__ aWih, const float* __restrict__ aWhh, const float* __restrict__ abih, const float* __restrict__ abhh,
    const float* __restrict__ cWih, const float* __restrict__ cWhh, const float* __restrict__ cbih, const float* __restrict__ cbhh,
    const float* __restrict__ vwW1, const float* __restrict__ awW1, const float* __restrict__ saW1)
{
  int idx = blockIdx.x*256 + threadIdx.x;
  if (idx >= PREP_TOT) return;
  if (idx < 2*B){ wsu[CTR+idx]=0u; return; } idx -= 2*B;
  if (idx < G4){ ws[BSUM_W+idx]=wbih[idx]+wbhh[idx]; return; } idx -= G4;
  if (idx < G4){ ws[BSUM_V+idx]=vbih[idx]+vbhh[idx]; return; } idx -= G4;
  if (idx < G4){ ws[BSUM_A+idx]=abih[idx]+abhh[idx]; return; } idx -= G4;
  if (idx < CG){ ws[BSUM_C+idx]=cbih[idx]+cbhh[idx]; return; } idx -= CG;
  if (idx < WIN*G4){ int k=idx/G4,g=idx%G4; ws[WIHT_W+idx]=wWih[g*WIN+k]; return; } idx -= WIN*G4;
  if (idx < VIN*G4){ int k=idx/G4,g=idx%G4; ws[WIHT_V+idx]=vWih[g*VIN+k]; return; } idx -= VIN*G4;
  if (idx < AIN*G4){ int k=idx/G4,g=idx%G4; ws[WIHT_A+idx]=aWih[g*AIN+k]; return; } idx -= AIN*G4;
  if (idx < H3*CG){ int k=idx/CG,g=idx%CG; ws[WIHT_C+idx]=cWih[g*H3+k]; return; } idx -= H3*CG;
  if (idx < H*G4){ int k=idx/G4,g=idx%G4; ws[WHHT_W+idx]=wWhh[g*H+k]; return; } idx -= H*G4;
  if (idx < H*G4){ int k=idx/G4,g=idx%G4; ws[WHHT_V+idx]=vWhh[g*H+k]; return; } idx -= H*G4;
  if (idx < H*G4){ int k=idx/G4,g=idx%G4; ws[WHHT_A+idx]=aWhh[g*H+k]; return; } idx -= H*G4;
  if (idx < H3*H3){ int k=idx/H3,d=idx%H3; ws[SAT_S+idx]=saW1[d*(2*H3)+k]; return; } idx -= H3*H3;
  if (idx < H3*H3){ int k=idx/H3,d=idx%H3; ws[SAT_T+idx]=saW1[d*(2*H3)+H3+k]; return; } idx -= H3*H3;
  if (idx < H*H){ int k=idx/H,d=idx%H; ws[VW_ST+idx]=vwW1[d*(2*H)+k]; return; } idx -= H*H;
  if (idx < H*H){ int k=idx/H,d=idx%H; ws[VW_TT+idx]=vwW1[d*(2*H)+H+k]; return; } idx -= H*H;
  if (idx < H*H){ int k=idx/H,d=idx%H; ws[AW_ST+idx]=awW1[d*(2*H)+k]; return; } idx -= H*H;
  if (idx < H*H){ int k=idx/H,d=idx%H; ws[AW_TT+idx]=awW1[d*(2*H)+H+k]; return; } idx -= H*H;
  // WRES: c_Whh -> f16x2, lane-swizzled so k6 residency loads are coalesced
  {
    int ul = idx & 127; int r = idx >> 7; int k2 = r % 192; int jj = r / 192;
    int sl = jj >> 2, j = jj & 3;
    int gate = j*H3 + sl*128 + ul;
    wsu[WRES+idx] = packh2(cWhh[gate*H3 + 2*k2], cWhh[gate*H3 + 2*k2 + 1]);
  }
}

// ---------------- K1: input projections xg for w/v/a LSTMs ----------------
// grid: 3 * B * (S/8) = 480 blocks, 256 threads
__global__ void k1_xg(float* __restrict__ ws,
    const float* __restrict__ xw, const float* __restrict__ xv, const float* __restrict__ xa)
{
  int bid = blockIdx.x;
  int lstm = bid/160; int rem = bid%160; int b = rem/20; int s0 = (rem%20)*8;
  int in_dim; const float* x; const float* wT; const float* bs; float* xg;
  if (lstm==0){ in_dim=WIN; x=xw; wT=ws+WIHT_W; bs=ws+BSUM_W; xg=ws+XG_W; }
  else if (lstm==1){ in_dim=VIN; x=xv; wT=ws+WIHT_V; bs=ws+BSUM_V; xg=ws+XG_V; }
  else { in_dim=AIN; x=xa; wT=ws+WIHT_A; bs=ws+BSUM_A; xg=ws+XG_A; }
  __shared__ float xt[8][WIN];
  int tid = threadIdx.x;
  for (int i=tid; i<8*in_dim; i+=256){ int r=i/in_dim, k=i%in_dim; xt[r][k] = x[((size_t)(b*S+s0+r))*in_dim + k]; }
  __syncthreads();
  float acc0[8], acc1[8];
  float b0 = bs[tid], b1 = bs[tid+256];
#pragma unroll
  for (int r=0;r<8;r++){ acc0[r]=b0; acc1[r]=b1; }
  for (int k=0;k<in_dim;k++){
    float w0 = wT[k*G4 + tid], w1 = wT[k*G4 + 256 + tid];
#pragma unroll
    for (int r=0;r<8;r++){ float xx = xt[r][k]; acc0[r] = fmaf(xx,w0,acc0[r]); acc1[r] = fmaf(xx,w1,acc1[r]); }
  }
#pragma unroll
  for (int r=0;r<8;r++){
    size_t ro = (size_t)(b*S+s0+r)*G4;
    xg[ro + tid] = acc0[r];
    xg[ro + 256 + tid] = acc1[r];
  }
}

// ---------------- K2: w/v/a LSTM recurrences (one block per lstm,batch) ----------------
// grid 24 blocks, 512 threads; Whh register-resident
__global__ __launch_bounds__(512,2) void k2_lstm(float* __restrict__ ws)
{
  int lstm = blockIdx.x >> 3, b = blockIdx.x & 7;
  const float* xg; const float* whhT; float* hs; float* cx = nullptr;
  if (lstm==0){ xg=ws+XG_W; whhT=ws+WHHT_W; hs=ws+HS_W; cx=ws+C_X; }
  else if (lstm==1){ xg=ws+XG_V; whhT=ws+WHHT_V; hs=ws+HS_V; }
  else { xg=ws+XG_A; whhT=ws+WHHT_A; hs=ws+HS_A; }
  int g = threadIdx.x;
  float wreg[H];
#pragma unroll
  for (int k=0;k<H;k++) wreg[k] = whhT[k*G4 + g];
  __shared__ __align__(16) float hbuf[H];
  __shared__ float gsum[G4];
  float c_reg = 0.f;
  if (g < H) hbuf[g] = 0.f;
  __syncthreads();
  const float* xgb = xg + (size_t)b*S*G4;
  float* hsb = hs + (size_t)b*S*H;
  float* cxb = cx ? cx + (size_t)b*S*H3 : nullptr;
  for (int t=0;t<S;t++){
    float acc = xgb[(size_t)t*G4 + g];
#pragma unroll
    for (int k4=0;k4<H/4;k4++){
      float4 h4 = ((const float4*)hbuf)[k4];
      acc = fmaf(wreg[4*k4+0], h4.x, acc);
      acc = fmaf(wreg[4*k4+1], h4.y, acc);
      acc = fmaf(wreg[4*k4+2], h4.z, acc);
      acc = fmaf(wreg[4*k4+3], h4.w, acc);
    }
    gsum[g] = acc;
    __syncthreads();
    if (g < H){
      float gi=gsum[g], gf=gsum[H+g], gg=gsum[2*H+g], go=gsum[3*H+g];
      c_reg = sigf(gf)*c_reg + sigf(gi)*tanhfast(gg);
      float h = sigf(go)*tanhfast(c_reg);
      hbuf[g] = h;
      hsb[(size_t)t*H + g] = h;
      if (cxb) cxb[(size_t)t*H3 + g] = h;
    }
    __syncthreads();
  }
}

// ---------------- K3a: attention projections (s/t for vw and aw) ----------------
// grid 4*B*(S/8)=640, 128 threads
__global__ void k3a_proj(float* __restrict__ ws, const float* __restrict__ vwb1, const float* __restrict__ awb1)
{
  int bid = blockIdx.x;
  int p = bid/160; int rem = bid%160; int b = rem/20; int s0 = (rem%20)*8;
  const float* src; const float* wT; const float* bias=nullptr; float* dst;
  if (p==0){ src=ws+HS_V; wT=ws+VW_ST; dst=ws+S_VW; }
  else if (p==1){ src=ws+HS_W; wT=ws+VW_TT; bias=vwb1; dst=ws+T_VW; }
  else if (p==2){ src=ws+HS_A; wT=ws+AW_ST; dst=ws+S_AW; }
  else { src=ws+HS_W; wT=ws+AW_TT; bias=awb1; dst=ws+T_AW; }
  __shared__ float xr[8][H];
  int tid = threadIdx.x;
  for (int i=tid;i<8*H;i+=128){ int r=i>>7, k=i&127; xr[r][k] = src[(size_t)(b*S+s0+r)*H + k]; }
  __syncthreads();
  float acc[8];
  float bv = bias ? bias[tid] : 0.f;
#pragma unroll
  for (int r=0;r<8;r++) acc[r]=bv;
  for (int k=0;k<H;k++){
    float wv = wT[k*H + tid];
#pragma unroll
    for (int r=0;r<8;r++) acc[r] = fmaf(xr[r][k], wv, acc[r]);
  }
#pragma unroll
  for (int r=0;r<8;r++) dst[(size_t)(b*S+s0+r)*H + tid] = acc[r];
}

// ---------------- K3b: vw/aw cross-attention (scores, softmax, out) ----------------
// grid 2*B*S/4 = 640 blocks of 256 (wave per (A,b,w) row)
__global__ void k3b_attn(float* __restrict__ ws, float* __restrict__ dout,
    const int* __restrict__ lengths, const float* __restrict__ vww2, const float* __restrict__ aww2)
{
  int wid = threadIdx.x >> 6, lane = threadIdx.x & 63;
  int row = blockIdx.x*4 + wid;
  int A = row / (B*S); int rem = row % (B*S); int b = rem / S; int w = rem % S;
  const float* sp = ws + (A? S_AW : S_VW) + (size_t)(b*S)*H;
  const float* tp = ws + (A? T_AW : T_VW) + (size_t)(b*S + w)*H;
  const float* w2 = A? aww2 : vww2;
  const float* src = ws + (A? HS_A : HS_V) + (size_t)(b*S)*H;
  float* attw = dout + (A? O_AATT : O_VATT) + (size_t)b*S*S + (size_t)w*S;
  int len = lengths[b];
  __shared__ float sc[4][S];
  float2 t2 = ((const float2*)tp)[lane];
  float2 w22 = ((const float2*)w2)[lane];
  for (int v=0; v<S; v++){
    float2 s2 = ((const float2*)(sp + (size_t)v*H))[lane];
    float x0 = tanhfast(t2.x + s2.x), x1 = tanhfast(t2.y + s2.y);
    float p = wred_sum(x0*w22.x + x1*w22.y);
    if (lane==0) sc[wid][v] = p;
  }
  __syncthreads();
  // softmax of mask*scores over 160 (3 slots per lane)
  float m0 = (lane      < len)? sc[wid][lane]     : 0.f;
  float m1 = (lane+64   < len)? sc[wid][lane+64]  : 0.f;
  float m2 = (lane<32) ? ((lane+128 < len)? sc[wid][lane+128] : 0.f) : -1e30f;
  float m = wred_max(fmaxf(fmaxf(m0,m1),m2));
  float e0 = __expf(m0-m), e1 = __expf(m1-m), e2 = (lane<32)? __expf(m2-m) : 0.f;
  float inv = 1.f / wred_sum(e0+e1+e2);
  e0*=inv; e1*=inv; e2*=inv;
  sc[wid][lane] = e0; sc[wid][lane+64] = e1; if (lane<32) sc[wid][128+lane] = e2;
  attw[lane] = e0; attw[lane+64] = e1; if (lane<32) attw[128+lane] = e2;
  __syncthreads();
  float2 acc; acc.x=0.f; acc.y=0.f;
  for (int v=0; v<S; v++){
    float wg = sc[wid][v];
    float2 sv = ((const float2*)(src + (size_t)v*H))[lane];
    acc.x = fmaf(wg, sv.x, acc.x); acc.y = fmaf(wg, sv.y, acc.y);
  }
  float* cxr = ws + C_X + (size_t)(b*S + w)*H3 + (A? 2*H : H);
  ((float2*)cxr)[lane] = acc;
}

// ---------------- K4: soft attention (v and a) ----------------
// grid 16 (A*8+b), 256 threads
__global__ void k4_soft(float* __restrict__ ws, float* __restrict__ dout,
    const float* __restrict__ mpw, const float* __restrict__ mpb)
{
  int A = blockIdx.x >> 3, b = blockIdx.x & 7;
  const float* reps = ws + (A? HS_A : HS_V) + (size_t)(b*S)*H;
  float* softw = dout + (A? O_ASOFT : O_VSOFT) + b*S;
  float* comp = ws + (A? ACOMP : VCOMP) + b*H;
  __shared__ float sc[S]; __shared__ float wg[S];
  int wid = threadIdx.x >> 6, lane = threadIdx.x & 63;
  float bb = mpb[0];
  for (int s=wid; s<S; s+=4){
    float2 r2 = ((const float2*)(reps + (size_t)s*H))[lane];
    float2 m2 = ((const float2*)mpw)[lane];
    float p = wred_sum(r2.x*m2.x + r2.y*m2.y);
    if (lane==0) sc[s] = p + bb;
  }
  __syncthreads();
  if (threadIdx.x < 64){
    float m0 = sc[lane], m1 = sc[lane+64], m2 = (lane<32)? sc[lane+128] : -1e30f;
    float m = wred_max(fmaxf(fmaxf(m0,m1),m2));
    float e0=__expf(m0-m), e1=__expf(m1-m), e2=(lane<32)?__expf(m2-m):0.f;
    float inv = 1.f / wred_sum(e0+e1+e2);
    e0*=inv; e1*=inv; e2*=inv;
    wg[lane]=e0; wg[lane+64]=e1; if (lane<32) wg[128+lane]=e2;
    softw[lane]=e0; softw[lane+64]=e1; if (lane<32) softw[128+lane]=e2;
  }
  __syncthreads();
  if (threadIdx.x < H){
    float acc=0.f;
    for (int s=0;s<S;s++) acc = fmaf(wg[s], reps[(size_t)s*H + threadIdx.x], acc);
    comp[threadIdx.x] = acc;
  }
}

// ---------------- K5: c-LSTM input projection ----------------
// grid B*40 (s-tile 4), 512 threads
__global__ void k5_xgc(float* __restrict__ ws, u32* __restrict__ wsu)
{
  int b = blockIdx.x/40; int s0 = (blockIdx.x%40)*4;
  const float* cxb = ws + C_X + (size_t)(b*S+s0)*H3;
  const float* wT = ws + WIHT_C;
  const float* bs = ws + BSUM_C;
  __half* xgc = (__half*)(wsu + XGC16);
  __shared__ float xr[4][H3];
  int tid = threadIdx.x;
  for (int i=tid;i<4*H3;i+=512){ int r=i/H3, k=i%H3; xr[r][k]=cxb[(size_t)r*H3+k]; }
  __syncthreads();
  float acc[4][3];
  float b0=bs[tid], b1=bs[tid+512], b2=bs[tid+1024];
#pragma unroll
  for (int r=0;r<4;r++){ acc[r][0]=b0; acc[r][1]=b1; acc[r][2]=b2; }
  for (int k=0;k<H3;k++){
    float w0=wT[(size_t)k*CG+tid], w1=wT[(size_t)k*CG+512+tid], w2v=wT[(size_t)k*CG+1024+tid];
#pragma unroll
    for (int r=0;r<4;r++){
      float xx = xr[r][k];
      acc[r][0]=fmaf(xx,w0,acc[r][0]); acc[r][1]=fmaf(xx,w1,acc[r][1]); acc[r][2]=fmaf(xx,w2v,acc[r][2]);
    }
  }
#pragma unroll
  for (int r=0;r<4;r++){
    size_t ro = (size_t)(b*S+s0+r)*CG;
    xgc[ro+tid] = __float2half_rn(acc[r][0]);
    xgc[ro+512+tid] = __float2half_rn(acc[r][1]);
    xgc[ro+1024+tid] = __float2half_rn(acc[r][2]);
  }
}

// ---------------- K6: c-LSTM recurrence ----------------
// 24 blocks = (slice<<3)|batch so a batch's 3 blocks hit the same XCD (mod-8 heuristic).
// 512 threads; each thread owns ONE gate row, f16x2 register-resident (192 VGPRs).
__global__ __launch_bounds__(512,2) void k6_clstm(float* __restrict__ ws, u32* __restrict__ wsu)
{
  int b = blockIdx.x & 7, sl = blockIdx.x >> 3;
  int tid = threadIdx.x, j = tid>>7, ul = tid&127;
  const u32* wres = wsu + WRES;
  const __half* xgc = (const __half*)(wsu + XGC16);
  u32* chsb = wsu + CHS16 + (size_t)b*S*(H3/2);
  u32* hxb = wsu + H_X + (size_t)b*2*(H3/2);
  u32* myctr = wsu + CTR + b*2;
  u32 wreg[192];
  const u32* wbase = wres + ((size_t)(sl*4+j)*192)*128 + ul;
#pragma unroll
  for (int k2=0;k2<192;k2++) wreg[k2] = wbase[(size_t)k2*128];
  __shared__ __align__(16) u32 h2[H3/2];
  __shared__ float gsum[G4];
  __shared__ float hloc[128];
  float c_reg = 0.f;
  if (tid < H3/2) h2[tid] = 0u;
  __syncthreads();
  const __half* xgb = xgc + (size_t)b*S*CG;
  int gate = j*H3 + sl*128 + ul;
  for (int t=0;t<S;t++){
    float acc = __half2float(xgb[(size_t)t*CG + gate]);
#pragma unroll
    for (int k8=0;k8<48;k8++){
      uint4 hh = ((const uint4*)h2)[k8];
      acc = fdot2f(wreg[4*k8+0], hh.x, acc);
      acc = fdot2f(wreg[4*k8+1], hh.y, acc);
      acc = fdot2f(wreg[4*k8+2], hh.z, acc);
      acc = fdot2f(wreg[4*k8+3], hh.w, acc);
    }
    gsum[tid] = acc;
    __syncthreads();
    if (tid < 128){
      float gi=gsum[tid], gf=gsum[128+tid], gg=gsum[256+tid], go=gsum[384+tid];
      c_reg = sigf(gf)*c_reg + sigf(gi)*tanhfast(gg);
      hloc[tid] = sigf(go)*tanhfast(c_reg);
    }
    __syncthreads();
    int par = t & 1;
    if (tid < 64){
      u32 pk = packh2(hloc[2*tid], hloc[2*tid+1]);
      h2[sl*64 + tid] = pk;
      chsb[(size_t)t*(H3/2) + sl*64 + tid] = pk;
      hxb[par*(H3/2) + sl*64 + tid] = pk;
    }
    __syncthreads();
    if (tid == 0){
      __hip_atomic_fetch_add(myctr + par, 1u, __ATOMIC_RELEASE, __HIP_MEMORY_SCOPE_AGENT);
      u32 target = 3u*((u32)(t>>1)+1u);
      while (__hip_atomic_load(myctr + par, __ATOMIC_RELAXED, __HIP_MEMORY_SCOPE_AGENT) < target){
        __builtin_amdgcn_s_sleep(1);
      }
      __builtin_amdgcn_fence(__ATOMIC_ACQUIRE, "agent");
    }
    __syncthreads();
    if (tid < 128){
      int psl = (tid < 64) ? ((sl+1)%3) : ((sl+2)%3);
      int off = psl*64 + (tid&63);
      u32 pv = __hip_atomic_load(hxb + par*(H3/2) + off, __ATOMIC_RELAXED, __HIP_MEMORY_SCOPE_AGENT);
      h2[off] = pv;
    }
    __syncthreads();
  }
}

// ---------------- K7a: sa source projection s_sa = c_hs @ saW1[:, :H3].T ----------------
// grid B*40 (v-tile 4), 384 threads
__global__ void k7a_sproj(float* __restrict__ ws, u32* __restrict__ wsu)
{
  int b = blockIdx.x/40; int v0 = (blockIdx.x%40)*4;
  const __half* chs = (const __half*)(wsu + CHS16);
  const float* wT = ws + SAT_S;
  __shared__ float xr[4][H3];
  int tid = threadIdx.x;
  for (int i=tid;i<4*H3;i+=384){ int r=i/H3, k=i%H3; xr[r][k] = __half2float(chs[(size_t)(b*S+v0+r)*H3 + k]); }
  __syncthreads();
  float acc[4] = {0.f,0.f,0.f,0.f};
  for (int k=0;k<H3;k++){
    float wv = wT[(size_t)k*H3 + tid];
#pragma unroll
    for (int r=0;r<4;r++) acc[r] = fmaf(xr[r][k], wv, acc[r]);
  }
#pragma unroll
  for (int r=0;r<4;r++) ws[S_SA + (size_t)(b*S+v0+r)*H3 + tid] = acc[r];
}

// ---------------- K7b: sa attention at the single needed row (lengths-1) ----------------
// grid B, 384 threads (6 waves)
__global__ void k7b_sa(float* __restrict__ ws, u32* __restrict__ wsu,
    const int* __restrict__ lengths, const float* __restrict__ sab1, const float* __restrict__ saw2)
{
  int b = blockIdx.x;
  int len = lengths[b]; int tr = len-1;
  const __half* chs = (const __half*)(wsu + CHS16);
  __shared__ float tv[H3]; __shared__ float chr[H3]; __shared__ float sc[S]; __shared__ float wg[S];
  int tid = threadIdx.x, wid = tid>>6, lane = tid&63;
  chr[tid] = __half2float(chs[(size_t)(b*S+tr)*H3 + tid]);
  __syncthreads();
  float acc = sab1[tid];
  for (int k=0;k<H3;k++) acc = fmaf(chr[k], ws[SAT_T + (size_t)k*H3 + tid], acc);
  tv[tid] = acc;
  __syncthreads();
  for (int v=wid; v<S; v+=6){
    const float* sr = ws + S_SA + (size_t)(b*S+v)*H3;
    float p = 0.f;
#pragma unroll
    for (int q=0;q<6;q++){
      int d = lane + 64*q;
      p = fmaf(tanhfast(tv[d] + sr[d]), saw2[d], p);
    }
    p = wred_sum(p);
    if (lane==0) sc[v] = p;
  }
  __syncthreads();
  if (tid < 64){
    float m0 = (lane<len)? sc[lane]:0.f;
    float m1 = (lane+64<len)? sc[lane+64]:0.f;
    float m2 = (lane<32)? ((lane+128<len)? sc[lane+128]:0.f) : -1e30f;
    float m = wred_max(fmaxf(fmaxf(m0,m1),m2));
    float e0=__expf(m0-m), e1=__expf(m1-m), e2=(lane<32)?__expf(m2-m):0.f;
    float inv = 1.f / wred_sum(e0+e1+e2);
    wg[lane]=e0*inv; wg[lane+64]=e1*inv; if (lane<32) wg[128+lane]=e2*inv;
  }
  __syncthreads();
  float o = 0.f;
  for (int v=0; v<S; v++) o = fmaf(wg[v], __half2float(chs[(size_t)(b*S+v)*H3 + tid]), o);
  ws[C_OUT + (size_t)b*H3 + tid] = o;
}

// ---------------- K8: final MLP ----------------
// grid B, 128 threads
__global__ void k8_mlp(float* __restrict__ ws, float* __restrict__ dout,
    const float* __restrict__ fc1W, const float* __restrict__ fc1b,
    const float* __restrict__ fc2W, const float* __restrict__ fc2b)
{
  int b = blockIdx.x, tid = threadIdx.x;
  __shared__ float feat[5*H]; __shared__ float r1[H];
  for (int i=tid;i<5*H;i+=128){
    float val;
    if (i < H3) val = ws[C_OUT + (size_t)b*H3 + i];
    else if (i < H3+H) val = ws[VCOMP + b*H + (i-H3)];
    else val = ws[ACOMP + b*H + (i-H3-H)];
    feat[i] = val;
  }
  __syncthreads();
  float acc = fc1b[tid];
  for (int k=0;k<5*H;k++) acc = fmaf(feat[k], fc1W[(size_t)tid*5*H + k], acc);
  r1[tid] = fmaxf(acc, 0.f) * fc2W[tid];
  __syncthreads();
  if (tid < 64){
    float p = r1[tid] + r1[tid+64];
    p = wred_sum(p);
    if (tid==0) dout[b] = p + fc2b[0];
  }
}

// ---------------- launch ----------------
extern "C" void kernel_launch(void* const* d_in, const int* in_sizes, int n_in,
                              void* d_out, int out_size, void* d_ws, size_t ws_size,
                              hipStream_t stream) {
  const float* xw = (const float*)d_in[0];
  const float* xv = (const float*)d_in[1];
  const float* xa = (const float*)d_in[2];
  const int* lengths = (const int*)d_in[3];
  const float* wWih=(const float*)d_in[4], *wWhh=(const float*)d_in[5], *wbih=(const float*)d_in[6], *wbhh=(const float*)d_in[7];
  const float* vWih=(const float*)d_in[8], *vWhh=(const float*)d_in[9], *vbih=(const float*)d_in[10], *vbhh=(const float*)d_in[11];
  const float* aWih=(const float*)d_in[12], *aWhh=(const float*)d_in[13], *abih=(const float*)d_in[14], *abhh=(const float*)d_in[15];
  const float* cWih=(const float*)d_in[16], *cWhh=(const float*)d_in[17], *cbih=(const float*)d_in[18], *cbhh=(const float*)d_in[19];
  const float* vwW1=(const float*)d_in[20], *vwb1=(const float*)d_in[21], *vww2=(const float*)d_in[22];
  const float* awW1=(const float*)d_in[23], *awb1=(const float*)d_in[24], *aww2=(const float*)d_in[25];
  const float* saW1=(const float*)d_in[26], *sab1=(const float*)d_in[27], *saw2=(const float*)d_in[28];
  const float* mpw=(const float*)d_in[29], *mpb=(const float*)d_in[30];
  const float* fc1W=(const float*)d_in[31], *fc1b=(const float*)d_in[32];
  const float* fc2W=(const float*)d_in[33], *fc2b=(const float*)d_in[34];
  float* ws = (float*)d_ws;
  u32* wsu = (u32*)d_ws;
  float* dout = (float*)d_out;

  hipLaunchKernelGGL(k0_prep, dim3((PREP_TOT+255)/256), dim3(256), 0, stream,
      ws, wsu, wWih,wWhh,wbih,wbhh, vWih,vWhh,vbih,vbhh, aWih,aWhh,abih,abhh,
      cWih,cWhh,cbih,cbhh, vwW1, awW1, saW1);
  hipLaunchKernelGGL(k1_xg, dim3(480), dim3(256), 0, stream, ws, xw, xv, xa);
  hipLaunchKernelGGL(k2_lstm, dim3(24), dim3(512), 0, stream, ws);
  hipLaunchKernelGGL(k3a_proj, dim3(640), dim3(128), 0, stream, ws, vwb1, awb1);
  hipLaunchKernelGGL(k3b_attn, dim3(640), dim3(256), 0, stream, ws, dout, lengths, vww2, aww2);
  hipLaunchKernelGGL(k4_soft, dim3(16), dim3(256), 0, stream, ws, dout, mpw, mpb);
  hipLaunchKernelGGL(k5_xgc, dim3(B*40), dim3(512), 0, stream, ws, wsu);
  hipLaunchKernelGGL(k6_clstm, dim3(24), dim3(512), 0, stream, ws, wsu);
  hipLaunchKernelGGL(k7a_sproj, dim3(B*40), dim3(384), 0, stream, ws, wsu);
  hipLaunchKernelGGL(k7b_sa, dim3(B), dim3(384), 0, stream, ws, wsu, lengths, sab1, saw2);
  hipLaunchKernelGGL(k8_mlp, dim3(B), dim3(128), 0, stream, ws, dout, fc1W, fc1b, fc2W, fc2b);
}

// Round 2
// 954.561 us; speedup vs baseline: 1.2311x; 1.2311x over previous
//
#include <hip/hip_runtime.h>
#include <hip/hip_fp16.h>

typedef unsigned int u32;
typedef unsigned long long u64;

// ---------------- problem sizes ----------------
#define B 8
#define S 160
#define H 128
#define H3 384
#define G4 512
#define CG 1536
#define WIN 300
#define VIN 35
#define AIN 74

// ---------------- workspace layout (float-word offsets) ----------------
#define XG_W   0
#define XG_V   (XG_W + B*S*G4)
#define XG_A   (XG_V + B*S*G4)
#define HS_W   (XG_A + B*S*G4)
#define HS_V   (HS_W + B*S*H)
#define HS_A   (HS_V + B*S*H)
#define S_VW   (HS_A + B*S*H)
#define T_VW   (S_VW + B*S*H)
#define S_AW   (T_VW + B*S*H)
#define T_AW   (S_AW + B*S*H)
#define C_X    (T_AW + B*S*H)
#define S_SA   (C_X + B*S*H3)
#define WIHT_W (S_SA + B*S*H3)
#define WIHT_V (WIHT_W + WIN*G4)
#define WIHT_A (WIHT_V + VIN*G4)
#define WIHT_C (WIHT_A + AIN*G4)
#define WHHT_W (WIHT_C + H3*CG)
#define WHHT_V (WHHT_W + H*G4)
#define WHHT_A (WHHT_V + H*G4)
#define SAT_S  (WHHT_A + H*G4)
#define SAT_T  (SAT_S + H3*H3)
#define VW_ST  (SAT_T + H3*H3)
#define VW_TT  (VW_ST + H*H)
#define AW_ST  (VW_TT + H*H)
#define AW_TT  (AW_ST + H*H)
#define BSUM_W (AW_TT + H*H)
#define BSUM_V (BSUM_W + G4)
#define BSUM_A (BSUM_V + G4)
#define BSUM_C (BSUM_A + G4)
#define VCOMP  (BSUM_C + CG)
#define ACOMP  (VCOMP + B*H)
#define C_OUT  (ACOMP + B*H)
// u32 regions
#define XGC16  (C_OUT + B*H3)
#define WRES   (XGC16 + B*S*CG/2)
#define CHS16  (WRES + CG*H3/2)
#define H_X    (CHS16 + B*S*H3/2)
// H_X: per batch, 2 parities x 3 slices x 64 lanes of u64 (seq<<32 | h-pair)
//      = B * 2 * 192 u64 = B * 2 * 384 u32

// ---------------- output layout ----------------
#define O_VATT  8
#define O_VSOFT (8 + B*S*S)
#define O_AATT  (O_VSOFT + B*S)
#define O_ASOFT (O_AATT + B*S*S)

// ---------------- helpers ----------------
__device__ __forceinline__ float sigf(float x){ return 1.f/(1.f+__expf(-x)); }
__device__ __forceinline__ float tanhfast(float x){ float e=__expf(2.f*x); return 1.f - 2.f/(e+1.f); }
__device__ __forceinline__ float wred_sum(float x){
#pragma unroll
  for (int o=32;o;o>>=1) x += __shfl_xor(x,o);
  return x;
}
__device__ __forceinline__ float wred_max(float x){
#pragma unroll
  for (int o=32;o;o>>=1) x = fmaxf(x,__shfl_xor(x,o));
  return x;
}
__device__ __forceinline__ u32 packh2(float lo, float hi){
  __half a=__float2half_rn(lo), b=__float2half_rn(hi);
  return ((u32)__half_as_ushort(b)<<16) | (u32)__half_as_ushort(a);
}

typedef _Float16 h2v __attribute__((ext_vector_type(2)));
#if defined(__has_builtin)
#if __has_builtin(__builtin_amdgcn_fdot2)
#define HAVE_FDOT2 1
#endif
#endif
__device__ __forceinline__ float fdot2f(u32 w, u32 h, float acc){
#ifdef HAVE_FDOT2
  return __builtin_amdgcn_fdot2(__builtin_bit_cast(h2v,w), __builtin_bit_cast(h2v,h), acc, false);
#else
  h2v a=__builtin_bit_cast(h2v,w), b=__builtin_bit_cast(h2v,h);
  return acc + (float)a.x*(float)b.x + (float)a.y*(float)b.y;
#endif
}

// ---------------- K0: prep (transposes, bias sums, f16 packs) ----------------
#define PREP_TOT (3*G4 + CG + WIN*G4 + VIN*G4 + AIN*G4 + H3*CG + 3*H*G4 + 2*H3*H3 + 4*H*H + CG*H3/2)
__global__ void k0_prep(float* __restrict__ ws, u32* __restrict__ wsu,
    const float* __restrict__ wWih, const float* __restrict__ wWhh, const float* __restrict__ wbih, const float* __restrict__ wbhh,
    const float* __restrict__ vWih, const float* __restrict__ vWhh, const float* __restrict__ vbih, const float* __restrict__ vbhh,
    const float* __restrict__ aWih, const float* __restrict__ aWhh, const float* __restrict__ abih, const float* __restrict__ abhh,
    const float* __restrict__ cWih, const float* __restrict__ cWhh, const float* __restrict__ cbih, const float* __restrict__ cbhh,
    const float* __restrict__ vwW1, const float* __restrict__ awW1, const float* __restrict__ saW1)
{
  int idx = blockIdx.x*256 + threadIdx.x;
  if (idx >= PREP_TOT) return;
  if (idx < G4){ ws[BSUM_W+idx]=wbih[idx]+wbhh[idx]; return; } idx -= G4;
  if (idx < G4){ ws[BSUM_V+idx]=vbih[idx]+vbhh[idx]; return; } idx -= G4;
  if (idx < G4){ ws[BSUM_A+idx]=abih[idx]+abhh[idx]; return; } idx -= G4;
  if (idx < CG){ ws[BSUM_C+idx]=cbih[idx]+cbhh[idx]; return; } idx -= CG;
  if (idx < WIN*G4){ int k=idx/G4,g=idx%G4; ws[WIHT_W+idx]=wWih[g*WIN+k]; return; } idx -= WIN*G4;
  if (idx < VIN*G4){ int k=idx/G4,g=idx%G4; ws[WIHT_V+idx]=vWih[g*VIN+k]; return; } idx -= VIN*G4;
  if (idx < AIN*G4){ int k=idx/G4,g=idx%G4; ws[WIHT_A+idx]=aWih[g*AIN+k]; return; } idx -= AIN*G4;
  if (idx < H3*CG){ int k=idx/CG,g=idx%CG; ws[WIHT_C+idx]=cWih[g*H3+k]; return; } idx -= H3*CG;
  if (idx < H*G4){ int k=idx/G4,g=idx%G4; ws[WHHT_W+idx]=wWhh[g*H+k]; return; } idx -= H*G4;
  if (idx < H*G4){ int k=idx/G4,g=idx%G4; ws[WHHT_V+idx]=vWhh[g*H+k]; return; } idx -= H*G4;
  if (idx < H*G4){ int k=idx/G4,g=idx%G4; ws[WHHT_A+idx]=aWhh[g*H+k]; return; } idx -= H*G4;
  if (idx < H3*H3){ int k=idx/H3,d=idx%H3; ws[SAT_S+idx]=saW1[d*(2*H3)+k]; return; } idx -= H3*H3;
  if (idx < H3*H3){ int k=idx/H3,d=idx%H3; ws[SAT_T+idx]=saW1[d*(2*H3)+H3+k]; return; } idx -= H3*H3;
  if (idx < H*H){ int k=idx/H,d=idx%H; ws[VW_ST+idx]=vwW1[d*(2*H)+k]; return; } idx -= H*H;
  if (idx < H*H){ int k=idx/H,d=idx%H; ws[VW_TT+idx]=vwW1[d*(2*H)+H+k]; return; } idx -= H*H;
  if (idx < H*H){ int k=idx/H,d=idx%H; ws[AW_ST+idx]=awW1[d*(2*H)+k]; return; } idx -= H*H;
  if (idx < H*H){ int k=idx/H,d=idx%H; ws[AW_TT+idx]=awW1[d*(2*H)+H+k]; return; } idx -= H*H;
  // WRES: c_Whh -> f16x2, lane-swizzled so k6 residency loads are coalesced
  {
    int ul = idx & 127; int r = idx >> 7; int k2 = r % 192; int jj = r / 192;
    int sl = jj >> 2, j = jj & 3;
    int gate = j*H3 + sl*128 + ul;
    wsu[WRES+idx] = packh2(cWhh[gate*H3 + 2*k2], cWhh[gate*H3 + 2*k2 + 1]);
  }
}

// ---------------- K1: input projections xg for w/v/a LSTMs ----------------
// grid: 3 * B * (S/8) = 480 blocks, 256 threads
__global__ void k1_xg(float* __restrict__ ws,
    const float* __restrict__ xw, const float* __restrict__ xv, const float* __restrict__ xa)
{
  int bid = blockIdx.x;
  int lstm = bid/160; int rem = bid%160; int b = rem/20; int s0 = (rem%20)*8;
  int in_dim; const float* x; const float* wT; const float* bs; float* xg;
  if (lstm==0){ in_dim=WIN; x=xw; wT=ws+WIHT_W; bs=ws+BSUM_W; xg=ws+XG_W; }
  else if (lstm==1){ in_dim=VIN; x=xv; wT=ws+WIHT_V; bs=ws+BSUM_V; xg=ws+XG_V; }
  else { in_dim=AIN; x=xa; wT=ws+WIHT_A; bs=ws+BSUM_A; xg=ws+XG_A; }
  __shared__ float xt[8][WIN];
  int tid = threadIdx.x;
  for (int i=tid; i<8*in_dim; i+=256){ int r=i/in_dim, k=i%in_dim; xt[r][k] = x[((size_t)(b*S+s0+r))*in_dim + k]; }
  __syncthreads();
  float acc0[8], acc1[8];
  float b0 = bs[tid], b1 = bs[tid+256];
#pragma unroll
  for (int r=0;r<8;r++){ acc0[r]=b0; acc1[r]=b1; }
  for (int k=0;k<in_dim;k++){
    float w0 = wT[k*G4 + tid], w1 = wT[k*G4 + 256 + tid];
#pragma unroll
    for (int r=0;r<8;r++){ float xx = xt[r][k]; acc0[r] = fmaf(xx,w0,acc0[r]); acc1[r] = fmaf(xx,w1,acc1[r]); }
  }
#pragma unroll
  for (int r=0;r<8;r++){
    size_t ro = (size_t)(b*S+s0+r)*G4;
    xg[ro + tid] = acc0[r];
    xg[ro + 256 + tid] = acc1[r];
  }
}

// ---------------- K2: w/v/a LSTM recurrences (one block per lstm,batch) ----------------
// grid 24 blocks, 512 threads; Whh register-resident (128 f32/thread).
// launch_bounds(512,1): full 256-VGPR budget so wreg does NOT spill.
__global__ __launch_bounds__(512,1) void k2_lstm(float* __restrict__ ws)
{
  int lstm = blockIdx.x >> 3, b = blockIdx.x & 7;
  const float* xg; const float* whhT; float* hs; float* cx = nullptr;
  if (lstm==0){ xg=ws+XG_W; whhT=ws+WHHT_W; hs=ws+HS_W; cx=ws+C_X; }
  else if (lstm==1){ xg=ws+XG_V; whhT=ws+WHHT_V; hs=ws+HS_V; }
  else { xg=ws+XG_A; whhT=ws+WHHT_A; hs=ws+HS_A; }
  int g = threadIdx.x;
  float wreg[H];
#pragma unroll
  for (int k=0;k<H;k++) wreg[k] = whhT[k*G4 + g];
  __shared__ __align__(16) float hbuf[H];
  __shared__ float gsum[G4];
  float c_reg = 0.f;
  if (g < H) hbuf[g] = 0.f;
  const float* xgb = xg + (size_t)b*S*G4;
  float* hsb = hs + (size_t)b*S*H;
  float* cxb = cx ? cx + (size_t)b*S*H3 : nullptr;
  float xg_cur = xgb[g];
  __syncthreads();
  for (int t=0;t<S;t++){
    float acc = xg_cur;
    float xg_nxt = (t+1<S) ? xgb[(size_t)(t+1)*G4 + g] : 0.f;
#pragma unroll
    for (int k4=0;k4<H/4;k4++){
      float4 h4 = ((const float4*)hbuf)[k4];
      acc = fmaf(wreg[4*k4+0], h4.x, acc);
      acc = fmaf(wreg[4*k4+1], h4.y, acc);
      acc = fmaf(wreg[4*k4+2], h4.z, acc);
      acc = fmaf(wreg[4*k4+3], h4.w, acc);
    }
    gsum[g] = acc;
    xg_cur = xg_nxt;
    __syncthreads();
    if (g < H){
      float gi=gsum[g], gf=gsum[H+g], gg=gsum[2*H+g], go=gsum[3*H+g];
      c_reg = sigf(gf)*c_reg + sigf(gi)*tanhfast(gg);
      float h = sigf(go)*tanhfast(c_reg);
      hbuf[g] = h;
      hsb[(size_t)t*H + g] = h;
      if (cxb) cxb[(size_t)t*H3 + g] = h;
    }
    __syncthreads();
  }
}

// ---------------- K3a: attention projections (s/t for vw and aw) ----------------
// grid 4*B*(S/8)=640, 128 threads
__global__ void k3a_proj(float* __restrict__ ws, const float* __restrict__ vwb1, const float* __restrict__ awb1)
{
  int bid = blockIdx.x;
  int p = bid/160; int rem = bid%160; int b = rem/20; int s0 = (rem%20)*8;
  const float* src; const float* wT; const float* bias=nullptr; float* dst;
  if (p==0){ src=ws+HS_V; wT=ws+VW_ST; dst=ws+S_VW; }
  else if (p==1){ src=ws+HS_W; wT=ws+VW_TT; bias=vwb1; dst=ws+T_VW; }
  else if (p==2){ src=ws+HS_A; wT=ws+AW_ST; dst=ws+S_AW; }
  else { src=ws+HS_W; wT=ws+AW_TT; bias=awb1; dst=ws+T_AW; }
  __shared__ float xr[8][H];
  int tid = threadIdx.x;
  for (int i=tid;i<8*H;i+=128){ int r=i>>7, k=i&127; xr[r][k] = src[(size_t)(b*S+s0+r)*H + k]; }
  __syncthreads();
  float acc[8];
  float bv = bias ? bias[tid] : 0.f;
#pragma unroll
  for (int r=0;r<8;r++) acc[r]=bv;
  for (int k=0;k<H;k++){
    float wv = wT[k*H + tid];
#pragma unroll
    for (int r=0;r<8;r++) acc[r] = fmaf(xr[r][k], wv, acc[r]);
  }
#pragma unroll
  for (int r=0;r<8;r++) dst[(size_t)(b*S+s0+r)*H + tid] = acc[r];
}

// ---------------- K3b: vw/aw cross-attention (scores, softmax, out) ----------------
// grid 2*B*S/4 = 640 blocks of 256 (wave per (A,b,w) row)
__global__ void k3b_attn(float* __restrict__ ws, float* __restrict__ dout,
    const int* __restrict__ lengths, const float* __restrict__ vww2, const float* __restrict__ aww2)
{
  int wid = threadIdx.x >> 6, lane = threadIdx.x & 63;
  int row = blockIdx.x*4 + wid;
  int A = row / (B*S); int rem = row % (B*S); int b = rem / S; int w = rem % S;
  const float* sp = ws + (A? S_AW : S_VW) + (size_t)(b*S)*H;
  const float* tp = ws + (A? T_AW : T_VW) + (size_t)(b*S + w)*H;
  const float* w2 = A? aww2 : vww2;
  const float* src = ws + (A? HS_A : HS_V) + (size_t)(b*S)*H;
  float* attw = dout + (A? O_AATT : O_VATT) + (size_t)b*S*S + (size_t)w*S;
  int len = lengths[b];
  __shared__ float sc[4][S];
  float2 t2 = ((const float2*)tp)[lane];
  float2 w22 = ((const float2*)w2)[lane];
  for (int v=0; v<S; v++){
    float2 s2 = ((const float2*)(sp + (size_t)v*H))[lane];
    float x0 = tanhfast(t2.x + s2.x), x1 = tanhfast(t2.y + s2.y);
    float p = wred_sum(x0*w22.x + x1*w22.y);
    if (lane==0) sc[wid][v] = p;
  }
  __syncthreads();
  // softmax of mask*scores over 160 (3 slots per lane)
  float m0 = (lane      < len)? sc[wid][lane]     : 0.f;
  float m1 = (lane+64   < len)? sc[wid][lane+64]  : 0.f;
  float m2 = (lane<32) ? ((lane+128 < len)? sc[wid][lane+128] : 0.f) : -1e30f;
  float m = wred_max(fmaxf(fmaxf(m0,m1),m2));
  float e0 = __expf(m0-m), e1 = __expf(m1-m), e2 = (lane<32)? __expf(m2-m) : 0.f;
  float inv = 1.f / wred_sum(e0+e1+e2);
  e0*=inv; e1*=inv; e2*=inv;
  sc[wid][lane] = e0; sc[wid][lane+64] = e1; if (lane<32) sc[wid][128+lane] = e2;
  attw[lane] = e0; attw[lane+64] = e1; if (lane<32) attw[128+lane] = e2;
  __syncthreads();
  float2 acc; acc.x=0.f; acc.y=0.f;
  for (int v=0; v<S; v++){
    float wg = sc[wid][v];
    float2 sv = ((const float2*)(src + (size_t)v*H))[lane];
    acc.x = fmaf(wg, sv.x, acc.x); acc.y = fmaf(wg, sv.y, acc.y);
  }
  float* cxr = ws + C_X + (size_t)(b*S + w)*H3 + (A? 2*H : H);
  ((float2*)cxr)[lane] = acc;
}

// ---------------- K4: soft attention (v and a) ----------------
// grid 16 (A*8+b), 256 threads
__global__ void k4_soft(float* __restrict__ ws, float* __restrict__ dout,
    const float* __restrict__ mpw, const float* __restrict__ mpb)
{
  int A = blockIdx.x >> 3, b = blockIdx.x & 7;
  const float* reps = ws + (A? HS_A : HS_V) + (size_t)(b*S)*H;
  float* softw = dout + (A? O_ASOFT : O_VSOFT) + b*S;
  float* comp = ws + (A? ACOMP : VCOMP) + b*H;
  __shared__ float sc[S]; __shared__ float wg[S];
  int wid = threadIdx.x >> 6, lane = threadIdx.x & 63;
  float bb = mpb[0];
  for (int s=wid; s<S; s+=4){
    float2 r2 = ((const float2*)(reps + (size_t)s*H))[lane];
    float2 m2 = ((const float2*)mpw)[lane];
    float p = wred_sum(r2.x*m2.x + r2.y*m2.y);
    if (lane==0) sc[s] = p + bb;
  }
  __syncthreads();
  if (threadIdx.x < 64){
    float m0 = sc[lane], m1 = sc[lane+64], m2 = (lane<32)? sc[lane+128] : -1e30f;
    float m = wred_max(fmaxf(fmaxf(m0,m1),m2));
    float e0=__expf(m0-m), e1=__expf(m1-m), e2=(lane<32)?__expf(m2-m):0.f;
    float inv = 1.f / wred_sum(e0+e1+e2);
    e0*=inv; e1*=inv; e2*=inv;
    wg[lane]=e0; wg[lane+64]=e1; if (lane<32) wg[128+lane]=e2;
    softw[lane]=e0; softw[lane+64]=e1; if (lane<32) softw[128+lane]=e2;
  }
  __syncthreads();
  if (threadIdx.x < H){
    float acc=0.f;
    for (int s=0;s<S;s++) acc = fmaf(wg[s], reps[(size_t)s*H + threadIdx.x], acc);
    comp[threadIdx.x] = acc;
  }
}

// ---------------- K5: c-LSTM input projection ----------------
// grid B*40 (s-tile 4), 512 threads
__global__ void k5_xgc(float* __restrict__ ws, u32* __restrict__ wsu)
{
  int b = blockIdx.x/40; int s0 = (blockIdx.x%40)*4;
  const float* cxb = ws + C_X + (size_t)(b*S+s0)*H3;
  const float* wT = ws + WIHT_C;
  const float* bs = ws + BSUM_C;
  __half* xgc = (__half*)(wsu + XGC16);
  __shared__ float xr[4][H3];
  int tid = threadIdx.x;
  for (int i=tid;i<4*H3;i+=512){ int r=i/H3, k=i%H3; xr[r][k]=cxb[(size_t)r*H3+k]; }
  __syncthreads();
  float acc[4][3];
  float b0=bs[tid], b1=bs[tid+512], b2=bs[tid+1024];
#pragma unroll
  for (int r=0;r<4;r++){ acc[r][0]=b0; acc[r][1]=b1; acc[r][2]=b2; }
  for (int k=0;k<H3;k++){
    float w0=wT[(size_t)k*CG+tid], w1=wT[(size_t)k*CG+512+tid], w2v=wT[(size_t)k*CG+1024+tid];
#pragma unroll
    for (int r=0;r<4;r++){
      float xx = xr[r][k];
      acc[r][0]=fmaf(xx,w0,acc[r][0]); acc[r][1]=fmaf(xx,w1,acc[r][1]); acc[r][2]=fmaf(xx,w2v,acc[r][2]);
    }
  }
#pragma unroll
  for (int r=0;r<4;r++){
    size_t ro = (size_t)(b*S+s0+r)*CG;
    xgc[ro+tid] = __float2half_rn(acc[r][0]);
    xgc[ro+512+tid] = __float2half_rn(acc[r][1]);
    xgc[ro+1024+tid] = __float2half_rn(acc[r][2]);
  }
}

// ---------------- K6: c-LSTM recurrence ----------------
// 24 blocks = (slice<<3)|batch. 512 threads; each thread owns ONE gate row,
// f16x2 register-resident (192 u32 VGPRs; launch_bounds(512,1) -> 256 budget).
// Per-step exchange: wave0 computes h (2 gates/lane), publishes 8B atomics
// (seq<<32 | h-pair) to MALL; waves 2-3 poll the two remote slices in parallel.
// Parity double-buffer + monotone seq => no resets, re-poison-safe.
__global__ __launch_bounds__(512,1) void k6_clstm(float* __restrict__ ws, u32* __restrict__ wsu)
{
  int b = blockIdx.x & 7, sl = blockIdx.x >> 3;
  int tid = threadIdx.x, j = tid>>7, ul = tid&127, lane = tid&63;
  const u32* wres = wsu + WRES;
  const __half* xgc = (const __half*)(wsu + XGC16);
  u32* chsb = wsu + CHS16 + (size_t)b*S*(H3/2);
  u64* hxb = (u64*)(wsu + H_X) + (size_t)b*2*192;   // [par][slice*64+lane]
  u32 wreg[192];
  const u32* wbase = wres + ((size_t)(sl*4+j)*192)*128 + ul;
#pragma unroll
  for (int k2=0;k2<192;k2++) wreg[k2] = wbase[(size_t)k2*128];
  __shared__ __align__(16) u32 h2[H3/2];
  __shared__ float gsum[G4];
  float c0 = 0.f, c1 = 0.f;
  if (tid < H3/2) h2[tid] = 0u;
  const __half* xgb = xgc + (size_t)b*S*CG;
  int gate = j*H3 + sl*128 + ul;
  float xg_cur = __half2float(xgb[gate]);
  __syncthreads();
  for (int t=0;t<S;t++){
    float acc = xg_cur;
    float xg_nxt = (t+1<S) ? __half2float(xgb[(size_t)(t+1)*CG + gate]) : 0.f;
#pragma unroll
    for (int k8=0;k8<48;k8++){
      uint4 hh = ((const uint4*)h2)[k8];
      acc = fdot2f(wreg[4*k8+0], hh.x, acc);
      acc = fdot2f(wreg[4*k8+1], hh.y, acc);
      acc = fdot2f(wreg[4*k8+2], hh.z, acc);
      acc = fdot2f(wreg[4*k8+3], hh.w, acc);
    }
    gsum[tid] = acc;
    xg_cur = xg_nxt;
    __syncthreads();
    int par = t & 1;
    u32 target = (u32)(t>>1) + 1u;
    if (tid < 64){
      // compute two h values (positions 2*lane, 2*lane+1 of this slice), publish
      int p0 = 2*lane, p1 = 2*lane+1;
      float gi0=gsum[p0], gf0=gsum[128+p0], gg0=gsum[256+p0], go0=gsum[384+p0];
      float gi1=gsum[p1], gf1=gsum[128+p1], gg1=gsum[256+p1], go1=gsum[384+p1];
      c0 = sigf(gf0)*c0 + sigf(gi0)*tanhfast(gg0);
      c1 = sigf(gf1)*c1 + sigf(gi1)*tanhfast(gg1);
      float h0 = sigf(go0)*tanhfast(c0);
      float h1 = sigf(go1)*tanhfast(c1);
      u32 pk = packh2(h0,h1);
      h2[sl*64 + lane] = pk;
      chsb[(size_t)t*(H3/2) + sl*64 + lane] = pk;
      __hip_atomic_store(&hxb[(size_t)par*192 + sl*64 + lane],
                         ((u64)target<<32) | (u64)pk,
                         __ATOMIC_RELAXED, __HIP_MEMORY_SCOPE_AGENT);
    } else if (tid >= 128 && tid < 256){
      // two 64-lane groups each pull one remote slice
      int grp = (tid-128)>>6;
      int psl = sl + 1 + grp; if (psl >= 3) psl -= 3;
      u64* src = &hxb[(size_t)par*192 + psl*64 + lane];
      u64 v;
      do {
        v = __hip_atomic_load(src, __ATOMIC_RELAXED, __HIP_MEMORY_SCOPE_AGENT);
      } while ((u32)(v>>32) != target);
      h2[psl*64 + lane] = (u32)v;
    }
    __syncthreads();
  }
}

// ---------------- K7a: sa source projection s_sa = c_hs @ saW1[:, :H3].T ----------------
// grid B*40 (v-tile 4), 384 threads
__global__ void k7a_sproj(float* __restrict__ ws, u32* __restrict__ wsu)
{
  int b = blockIdx.x/40; int v0 = (blockIdx.x%40)*4;
  const __half* chs = (const __half*)(wsu + CHS16);
  const float* wT = ws + SAT_S;
  __shared__ float xr[4][H3];
  int tid = threadIdx.x;
  for (int i=tid;i<4*H3;i+=384){ int r=i/H3, k=i%H3; xr[r][k] = __half2float(chs[(size_t)(b*S+v0+r)*H3 + k]); }
  __syncthreads();
  float acc[4] = {0.f,0.f,0.f,0.f};
  for (int k=0;k<H3;k++){
    float wv = wT[(size_t)k*H3 + tid];
#pragma unroll
    for (int r=0;r<4;r++) acc[r] = fmaf(xr[r][k], wv, acc[r]);
  }
#pragma unroll
  for (int r=0;r<4;r++) ws[S_SA + (size_t)(b*S+v0+r)*H3 + tid] = acc[r];
}

// ---------------- K7b: sa attention at the single needed row (lengths-1) ----------------
// grid B, 384 threads (6 waves)
__global__ void k7b_sa(float* __restrict__ ws, u32* __restrict__ wsu,
    const int* __restrict__ lengths, const float* __restrict__ sab1, const float* __restrict__ saw2)
{
  int b = blockIdx.x;
  int len = lengths[b]; int tr = len-1;
  const __half* chs = (const __half*)(wsu + CHS16);
  __shared__ float tv[H3]; __shared__ float chr[H3]; __shared__ float sc[S]; __shared__ float wg[S];
  int tid = threadIdx.x, wid = tid>>6, lane = tid&63;
  chr[tid] = __half2float(chs[(size_t)(b*S+tr)*H3 + tid]);
  __syncthreads();
  float acc = sab1[tid];
  for (int k=0;k<H3;k++) acc = fmaf(chr[k], ws[SAT_T + (size_t)k*H3 + tid], acc);
  tv[tid] = acc;
  __syncthreads();
  for (int v=wid; v<S; v+=6){
    const float* sr = ws + S_SA + (size_t)(b*S+v)*H3;
    float p = 0.f;
#pragma unroll
    for (int q=0;q<6;q++){
      int d = lane + 64*q;
      p = fmaf(tanhfast(tv[d] + sr[d]), saw2[d], p);
    }
    p = wred_sum(p);
    if (lane==0) sc[v] = p;
  }
  __syncthreads();
  if (tid < 64){
    float m0 = (lane<len)? sc[lane]:0.f;
    float m1 = (lane+64<len)? sc[lane+64]:0.f;
    float m2 = (lane<32)? ((lane+128<len)? sc[lane+128]:0.f) : -1e30f;
    float m = wred_max(fmaxf(fmaxf(m0,m1),m2));
    float e0=__expf(m0-m), e1=__expf(m1-m), e2=(lane<32)?__expf(m2-m):0.f;
    float inv = 1.f / wred_sum(e0+e1+e2);
    wg[lane]=e0*inv; wg[lane+64]=e1*inv; if (lane<32) wg[128+lane]=e2*inv;
  }
  __syncthreads();
  float o = 0.f;
  for (int v=0; v<S; v++) o = fmaf(wg[v], __half2float(chs[(size_t)(b*S+v)*H3 + tid]), o);
  ws[C_OUT + (size_t)b*H3 + tid] = o;
}

// ---------------- K8: final MLP ----------------
// grid B, 128 threads
__global__ void k8_mlp(float* __restrict__ ws, float* __restrict__ dout,
    const float* __restrict__ fc1W, const float* __restrict__ fc1b,
    const float* __restrict__ fc2W, const float* __restrict__ fc2b)
{
  int b = blockIdx.x, tid = threadIdx.x;
  __shared__ float feat[5*H]; __shared__ float r1[H];
  for (int i=tid;i<5*H;i+=128){
    float val;
    if (i < H3) val = ws[C_OUT + (size_t)b*H3 + i];
    else if (i < H3+H) val = ws[VCOMP + b*H + (i-H3)];
    else val = ws[ACOMP + b*H + (i-H3-H)];
    feat[i] = val;
  }
  __syncthreads();
  float acc = fc1b[tid];
  for (int k=0;k<5*H;k++) acc = fmaf(feat[k], fc1W[(size_t)tid*5*H + k], acc);
  r1[tid] = fmaxf(acc, 0.f) * fc2W[tid];
  __syncthreads();
  if (tid < 64){
    float p = r1[tid] + r1[tid+64];
    p = wred_sum(p);
    if (tid==0) dout[b] = p + fc2b[0];
  }
}

// ---------------- launch ----------------
extern "C" void kernel_launch(void* const* d_in, const int* in_sizes, int n_in,
                              void* d_out, int out_size, void* d_ws, size_t ws_size,
                              hipStream_t stream) {
  const float* xw = (const float*)d_in[0];
  const float* xv = (const float*)d_in[1];
  const float* xa = (const float*)d_in[2];
  const int* lengths = (const int*)d_in[3];
  const float* wWih=(const float*)d_in[4], *wWhh=(const float*)d_in[5], *wbih=(const float*)d_in[6], *wbhh=(const float*)d_in[7];
  const float* vWih=(const float*)d_in[8], *vWhh=(const float*)d_in[9], *vbih=(const float*)d_in[10], *vbhh=(const float*)d_in[11];
  const float* aWih=(const float*)d_in[12], *aWhh=(const float*)d_in[13], *abih=(const float*)d_in[14], *abhh=(const float*)d_in[15];
  const float* cWih=(const float*)d_in[16], *cWhh=(const float*)d_in[17], *cbih=(const float*)d_in[18], *cbhh=(const float*)d_in[19];
  const float* vwW1=(const float*)d_in[20], *vwb1=(const float*)d_in[21], *vww2=(const float*)d_in[22];
  const float* awW1=(const float*)d_in[23], *awb1=(const float*)d_in[24], *aww2=(const float*)d_in[25];
  const float* saW1=(const float*)d_in[26], *sab1=(const float*)d_in[27], *saw2=(const float*)d_in[28];
  const float* mpw=(const float*)d_in[29], *mpb=(const float*)d_in[30];
  const float* fc1W=(const float*)d_in[31], *fc1b=(const float*)d_in[32];
  const float* fc2W=(const float*)d_in[33], *fc2b=(const float*)d_in[34];
  float* ws = (float*)d_ws;
  u32* wsu = (u32*)d_ws;
  float* dout = (float*)d_out;

  hipLaunchKernelGGL(k0_prep, dim3((PREP_TOT+255)/256), dim3(256), 0, stream,
      ws, wsu, wWih,wWhh,wbih,wbhh, vWih,vWhh,vbih,vbhh, aWih,aWhh,abih,abhh,
      cWih,cWhh,cbih,cbhh, vwW1, awW1, saW1);
  hipLaunchKernelGGL(k1_xg, dim3(480), dim3(256), 0, stream, ws, xw, xv, xa);
  hipLaunchKernelGGL(k2_lstm, dim3(24), dim3(512), 0, stream, ws);
  hipLaunchKernelGGL(k3a_proj, dim3(640), dim3(128), 0, stream, ws, vwb1, awb1);
  hipLaunchKernelGGL(k3b_attn, dim3(640), dim3(256), 0, stream, ws, dout, lengths, vww2, aww2);
  hipLaunchKernelGGL(k4_soft, dim3(16), dim3(256), 0, stream, ws, dout, mpw, mpb);
  hipLaunchKernelGGL(k5_xgc, dim3(B*40), dim3(512), 0, stream, ws, wsu);
  hipLaunchKernelGGL(k6_clstm, dim3(24), dim3(512), 0, stream, ws, wsu);
  hipLaunchKernelGGL(k7a_sproj, dim3(B*40), dim3(384), 0, stream, ws, wsu);
  hipLaunchKernelGGL(k7b_sa, dim3(B), dim3(384), 0, stream, ws, wsu, lengths, sab1, saw2);
  hipLaunchKernelGGL(k8_mlp, dim3(B), dim3(128), 0, stream, ws, dout, fc1W, fc1b, fc2W, fc2b);
}